// Round 1
// baseline (8838.967 us; speedup 1.0000x reference)
//
#include <hip/hip_runtime.h>
#include <math.h>

#define NN 10000
#define NE 160000
#define DIM 480
#define NSH 9
#define NBASIS 128
#define NHEAD 4
#define HDIM 120
#define NL 6
#define NG 256
#define NS 128
#define FCH 64
#define CUTOFF 5.0f

__device__ __forceinline__ float silu_f(float v) { return v / (1.0f + __expf(-v)); }

// ---------------- geometry: sh + dist ----------------
__global__ void k_geom(const float* __restrict__ pos, const int* __restrict__ esrc,
                       const int* __restrict__ edst, float* __restrict__ sh,
                       float* __restrict__ dist)
{
  int e = blockIdx.x * 256 + threadIdx.x;
  if (e >= NE) return;
  int s = esrc[e], d = edst[e];
  float vx = pos[s*3+0] - pos[d*3+0];
  float vy = pos[s*3+1] - pos[d*3+1];
  float vz = pos[s*3+2] - pos[d*3+2];
  float r = sqrtf(vx*vx + vy*vy + vz*vz);
  dist[e] = r;
  float inv = 1.0f / (r + 1e-9f);
  float x = vx*inv, y = vy*inv, z = vz*inv;
  const float s3 = 1.7320508075688772f;
  const float s15 = 3.872983346207417f;
  const float s5 = 2.23606797749979f;
  float* o = sh + (size_t)e * NSH;
  o[0] = 1.0f;
  o[1] = s3*x; o[2] = s3*y; o[3] = s3*z;
  o[4] = s15*x*y; o[5] = s15*y*z; o[6] = 0.5f*s5*(3.0f*z*z - 1.0f);
  o[7] = s15*x*z; o[8] = 0.5f*s15*(x*x - y*y);
}

// ---------------- CSR build ----------------
__global__ void k_zero_int(int* p, int n)
{
  int i = blockIdx.x * 256 + threadIdx.x;
  if (i < n) p[i] = 0;
}

__global__ void k_count(const int* __restrict__ edst, int* __restrict__ cnt)
{
  int e = blockIdx.x * 256 + threadIdx.x;
  if (e < NE) atomicAdd(&cnt[edst[e]], 1);
}

__global__ __launch_bounds__(1024)
void k_scan(const int* __restrict__ cnt, int* __restrict__ row_ptr)
{
  __shared__ int part[1024];
  int tid = threadIdx.x;
  const int per = 10;                    // 1024*10 >= NN
  int base = tid * per;
  int s = 0;
  for (int i = 0; i < per; i++) { int idx = base + i; if (idx < NN) s += cnt[idx]; }
  part[tid] = s; __syncthreads();
  for (int off = 1; off < 1024; off <<= 1) {
    int v = (tid >= off) ? part[tid - off] : 0;
    __syncthreads();
    part[tid] += v;
    __syncthreads();
  }
  int run = (tid > 0) ? part[tid - 1] : 0;
  for (int i = 0; i < per; i++) {
    int idx = base + i;
    if (idx < NN) { row_ptr[idx] = run; run += cnt[idx]; }
  }
  if (tid == 1023) row_ptr[NN] = part[1023];
}

__global__ void k_fill(const int* __restrict__ edst, const int* __restrict__ row_ptr,
                       int* __restrict__ cursor, int* __restrict__ csr)
{
  int e = blockIdx.x * 256 + threadIdx.x;
  if (e >= NE) return;
  int d = edst[e];
  int p = atomicAdd(&cursor[d], 1);
  csr[row_ptr[d] + p] = e;
}

// ---------------- radial MLP (rb -> silu -> silu), h2 out [E,64] ----------------
__global__ __launch_bounds__(256)
void k_radial(const float* __restrict__ dist, const float* __restrict__ w1,
              const float* __restrict__ w2, float* __restrict__ h2out)
{
  __shared__ float rbs[NBASIS][65];     // rb tile [k][e]; reused as h1s [k][e]
  __shared__ float wsm[NBASIS * FCH];   // w1 then w2
  __shared__ float ds[64];
  int tid = threadIdx.x;
  int e0 = blockIdx.x * 64;
  if (tid < 64) {
    int e = e0 + tid;
    ds[tid] = (e < NE) ? dist[e] : 1e9f;
  }
  for (int i = tid; i < NBASIS * FCH; i += 256) wsm[i] = w1[i];
  __syncthreads();
  const float invw = (float)NBASIS / CUTOFF;
  for (int i = tid; i < NBASIS * 64; i += 256) {
    int k = i >> 6, e = i & 63;
    float c = k * (CUTOFF / 127.0f);
    float tt = (ds[e] - c) * invw;
    rbs[k][e] = __expf(-0.5f * tt * tt);
  }
  __syncthreads();
  int ty = tid >> 4, tx = tid & 15;
  float acc1[4][4] = {};
  for (int k = 0; k < NBASIS; k++) {
    float b[4];
#pragma unroll
    for (int j = 0; j < 4; j++) b[j] = wsm[k*FCH + tx*4 + j];
#pragma unroll
    for (int i = 0; i < 4; i++) {
      float a = rbs[k][ty*4 + i];
#pragma unroll
      for (int j = 0; j < 4; j++) acc1[i][j] = fmaf(a, b[j], acc1[i][j]);
    }
  }
  __syncthreads();
  // h1 (silu) transposed into rbs[k=col][e]; stage w2
#pragma unroll
  for (int i = 0; i < 4; i++)
#pragma unroll
    for (int j = 0; j < 4; j++)
      rbs[tx*4 + j][ty*4 + i] = silu_f(acc1[i][j]);
  for (int i = tid; i < FCH * FCH; i += 256) wsm[i] = w2[i];
  __syncthreads();
  float acc2[4][4] = {};
  for (int k = 0; k < FCH; k++) {
    float b[4];
#pragma unroll
    for (int j = 0; j < 4; j++) b[j] = wsm[k*FCH + tx*4 + j];
#pragma unroll
    for (int i = 0; i < 4; i++) {
      float a = rbs[k][ty*4 + i];
#pragma unroll
      for (int j = 0; j < 4; j++) acc2[i][j] = fmaf(a, b[j], acc2[i][j]);
    }
  }
#pragma unroll
  for (int i = 0; i < 4; i++) {
    int e = e0 + ty*4 + i;
    if (e >= NE) continue;
#pragma unroll
    for (int j = 0; j < 4; j++)
      h2out[(size_t)e*FCH + tx*4 + j] = silu_f(acc2[i][j]);
  }
}

// ---------------- layernorm (generic strides) ----------------
__global__ __launch_bounds__(256)
void k_ln(const float* __restrict__ in, float* __restrict__ out,
          int n, int cols, int in_stride, int out_stride)
{
  int wave = blockIdx.x * 4 + (threadIdx.x >> 6);
  int lane = threadIdx.x & 63;
  if (wave >= n) return;
  const float* r = in + (size_t)wave * in_stride;
  float s = 0.f, ss = 0.f;
  for (int c = lane; c < cols; c += 64) { float v = r[c]; s += v; ss += v*v; }
  for (int off = 32; off > 0; off >>= 1) { s += __shfl_down(s, off); ss += __shfl_down(ss, off); }
  s = __shfl(s, 0); ss = __shfl(ss, 0);
  float mu = s / cols;
  float var = ss / cols - mu * mu;
  float rstd = rsqrtf(fmaxf(var, 0.f) + 1e-5f);
  float* o = out + (size_t)wave * out_stride;
  for (int c = lane; c < cols; c += 64) o[c] = (r[c] - mu) * rstd;
}

// ---------------- tiled f32 GEMM: C[M,Nc] (=|+=) (silu?)(A[M,K] @ B[K,Nc]) ----------------
template<int ADD, int SILU>
__global__ __launch_bounds__(256)
void k_gemm(const float* __restrict__ A, const float* __restrict__ B,
            float* __restrict__ C, int M, int K, int Nc)
{
  __shared__ float As[16][129];   // [k][row], BM=128
  __shared__ float Bs[16][64];    // [k][col], BN=64
  int tid = threadIdx.x;
  int ty = tid >> 4, tx = tid & 15;
  int row0 = blockIdx.x * 128;
  int col0 = blockIdx.y * 64;
  float acc[8][4] = {};
  for (int k0 = 0; k0 < K; k0 += 16) {
#pragma unroll
    for (int c = 0; c < 2; c++) {
      int chunk = tid + c * 256;          // 512 float4 chunks
      int row_l = chunk >> 2;
      int kk = (chunk & 3) << 2;
      int grow = row0 + row_l;
      float4 v = make_float4(0.f, 0.f, 0.f, 0.f);
      if (grow < M) v = *(const float4*)(A + (size_t)grow * K + k0 + kk);
      As[kk][row_l] = v.x; As[kk+1][row_l] = v.y; As[kk+2][row_l] = v.z; As[kk+3][row_l] = v.w;
    }
    {
      int kk = tid >> 4;
      int c = (tid & 15) << 2;
      float4 v = make_float4(0.f, 0.f, 0.f, 0.f);
      if (col0 + c < Nc) v = *(const float4*)(B + (size_t)(k0 + kk) * Nc + col0 + c);
      *(float4*)&Bs[kk][c] = v;
    }
    __syncthreads();
#pragma unroll
    for (int kk = 0; kk < 16; kk++) {
      float b[4];
#pragma unroll
      for (int j = 0; j < 4; j++) b[j] = Bs[kk][tx*4 + j];
#pragma unroll
      for (int i = 0; i < 8; i++) {
        float a = As[kk][ty*8 + i];
#pragma unroll
        for (int j = 0; j < 4; j++) acc[i][j] = fmaf(a, b[j], acc[i][j]);
      }
    }
    __syncthreads();
  }
#pragma unroll
  for (int i = 0; i < 8; i++) {
    int row = row0 + ty*8 + i;
    if (row >= M) continue;
#pragma unroll
    for (int j = 0; j < 4; j++) {
      int col = col0 + tx*4 + j;
      if (col >= Nc) continue;
      float v = acc[i][j];
      if (SILU) v = silu_f(v);
      float* p = C + (size_t)row * Nc + col;
      if (ADD) *p += v; else *p = v;
    }
  }
}

// ---------------- per-edge msg -> logits ----------------
__global__ __launch_bounds__(512)
void k_logits(const int* __restrict__ esrc, const float* __restrict__ h2,
              const float* __restrict__ sh, const float* __restrict__ w3,
              const float* __restrict__ wsh, const float* __restrict__ aa,
              const float* __restrict__ y, float* __restrict__ logits)
{
  __shared__ __align__(16) float h2s[64];
  __shared__ float shs[9];
  __shared__ int srcs;
  __shared__ float prods[DIM];
  int t = threadIdx.x;
  float w3c[64];
#pragma unroll
  for (int k = 0; k < 64; k++) w3c[k] = (t < DIM) ? w3[k*DIM + t] : 0.f;
  float wshc[9];
#pragma unroll
  for (int j = 0; j < 9; j++) wshc[j] = (t < DIM) ? wsh[j*DIM + t] : 0.f;
  float ac = (t < DIM) ? aa[t] : 0.f;
  for (int e = blockIdx.x; e < NE; e += gridDim.x) {
    if (t < 64) h2s[t] = h2[(size_t)e*FCH + t];
    else if (t < 73) shs[t-64] = sh[(size_t)e*NSH + (t-64)];
    else if (t == 73) srcs = esrc[e];
    __syncthreads();
    if (t < DIM) {
      float gate = 0.f;
      const float4* h4 = (const float4*)h2s;
#pragma unroll
      for (int k = 0; k < 16; k++) {
        float4 hv = h4[k];
        gate = fmaf(hv.x, w3c[4*k+0], gate);
        gate = fmaf(hv.y, w3c[4*k+1], gate);
        gate = fmaf(hv.z, w3c[4*k+2], gate);
        gate = fmaf(hv.w, w3c[4*k+3], gate);
      }
      float sw = 0.f;
#pragma unroll
      for (int q = 0; q < 9; q++) sw = fmaf(shs[q], wshc[q], sw);
      float v = y[(size_t)srcs*DIM + t];
      float m = v * sw * gate;
      float lr = (m > 0.f) ? m : 0.2f * m;
      prods[t] = lr * ac;
    }
    __syncthreads();
    if (t < 256) {
      int h = t >> 6, lane = t & 63;
      float v2 = prods[h*HDIM + lane];
      if (lane < 56) v2 += prods[h*HDIM + 64 + lane];
      for (int off = 32; off > 0; off >>= 1) v2 += __shfl_down(v2, off);
      if (lane == 0) logits[(size_t)e*NHEAD + h] = v2;
    }
    __syncthreads();
  }
}

// ---------------- segment softmax (per dst, per head) ----------------
__global__ void k_alpha(const int* __restrict__ row_ptr, const int* __restrict__ csr,
                        const float* __restrict__ logits, float* __restrict__ alpha)
{
  int i = blockIdx.x * 256 + threadIdx.x;
  if (i >= NN * NHEAD) return;
  int d = i >> 2, h = i & 3;
  int beg = row_ptr[d], end = row_ptr[d+1];
  if (beg == end) return;
  float m = -1e30f;
  for (int j = beg; j < end; j++) m = fmaxf(m, logits[(size_t)csr[j]*NHEAD + h]);
  float s = 0.f;
  for (int j = beg; j < end; j++) {
    float ex = __expf(logits[(size_t)csr[j]*NHEAD + h] - m);
    alpha[(size_t)csr[j]*NHEAD + h] = ex;
    s += ex;
  }
  float inv = 1.f / (s + 1e-9f);
  for (int j = beg; j < end; j++) alpha[(size_t)csr[j]*NHEAD + h] *= inv;
}

// ---------------- CSR gather-reduce: deg-embed (DEG) or attention agg ----------------
template<bool DEG>
__global__ __launch_bounds__(512)
void k_gather_agg(const int* __restrict__ row_ptr, const int* __restrict__ csr,
                  const int* __restrict__ esrc, const float* __restrict__ h2,
                  const float* __restrict__ sh, const float* __restrict__ w3,
                  const float* __restrict__ wsh, const float* __restrict__ alpha,
                  const float* __restrict__ y, const int* __restrict__ z,
                  const float* __restrict__ emb, float* __restrict__ outx)
{
  __shared__ __align__(16) float h2s[64];
  __shared__ float shs[9];
  __shared__ float alphas[4];
  __shared__ int srcs;
  int t = threadIdx.x;
  float w3c[64];
#pragma unroll
  for (int k = 0; k < 64; k++) w3c[k] = (t < DIM) ? w3[k*DIM + t] : 0.f;
  float wshc[9];
#pragma unroll
  for (int j = 0; j < 9; j++) wshc[j] = (t < DIM) ? wsh[j*DIM + t] : 0.f;
  int head = (t < DIM) ? (t / HDIM) : 0;
  for (int d = blockIdx.x; d < NN; d += gridDim.x) {
    int beg = row_ptr[d], end = row_ptr[d+1];
    float acc = 0.f;
    for (int j = beg; j < end; j++) {
      int e = csr[j];
      if (t < 64) h2s[t] = h2[(size_t)e*FCH + t];
      else if (t < 73) shs[t-64] = sh[(size_t)e*NSH + (t-64)];
      else if (!DEG && t >= 73 && t < 77) alphas[t-73] = alpha[(size_t)e*NHEAD + (t-73)];
      else if (t == 77) srcs = esrc[e];
      __syncthreads();
      if (t < DIM) {
        float gate = 0.f;
        const float4* h4 = (const float4*)h2s;
#pragma unroll
        for (int k = 0; k < 16; k++) {
          float4 hv = h4[k];
          gate = fmaf(hv.x, w3c[4*k+0], gate);
          gate = fmaf(hv.y, w3c[4*k+1], gate);
          gate = fmaf(hv.z, w3c[4*k+2], gate);
          gate = fmaf(hv.w, w3c[4*k+3], gate);
        }
        float sw = 0.f;
#pragma unroll
        for (int q = 0; q < 9; q++) sw = fmaf(shs[q], wshc[q], sw);
        float v = DEG ? 1.f : y[(size_t)srcs*DIM + t];
        float m = v * sw * gate;
        acc += m * (DEG ? (1.0f/16.0f) : alphas[head]);
      }
      __syncthreads();
    }
    if (t < DIM) {
      if (DEG) outx[(size_t)d*DIM + t] = emb[(size_t)z[d]*DIM + t] + acc;
      else     outx[(size_t)d*DIM + t] = acc;
    }
  }
}

// ---------------- final scatter over molecules ----------------
__global__ void k_scatter(const float* __restrict__ h, const int* __restrict__ batch,
                          float* __restrict__ out)
{
  int i = blockIdx.x * 256 + threadIdx.x;
  if (i >= NN * NS) return;
  int n = i >> 7;
  int c = i & 127;
  atomicAdd(&out[(size_t)batch[n]*NS + c], h[i] * 0.23570226039551584f);  // 1/sqrt(18)
}

extern "C" void kernel_launch(void* const* d_in, const int* in_sizes, int n_in,
                              void* d_out, int out_size, void* d_ws, size_t ws_size,
                              hipStream_t stream)
{
  const int*   z        = (const int*)  d_in[0];
  const float* pos      = (const float*)d_in[1];
  const int*   batch    = (const int*)  d_in[2];
  const int*   esrc     = (const int*)  d_in[3];
  const int*   edst     = (const int*)  d_in[4];
  const float* atom_emb = (const float*)d_in[5];
  const float* W_deg_sh = (const float*)d_in[6];
  const float* deg_w1   = (const float*)d_in[7];
  const float* deg_w2   = (const float*)d_in[8];
  const float* deg_w3   = (const float*)d_in[9];
  const float* Wv       = (const float*)d_in[10];
  const float* Wsh      = (const float*)d_in[11];
  const float* rad_w1   = (const float*)d_in[12];
  const float* rad_w2   = (const float*)d_in[13];
  const float* rad_w3   = (const float*)d_in[14];
  const float* attn_a   = (const float*)d_in[15];
  const float* Wo       = (const float*)d_in[16];
  const float* ffn_w1   = (const float*)d_in[17];
  const float* ffn_w2   = (const float*)d_in[18];
  const float* head_w1  = (const float*)d_in[19];
  const float* head_w2  = (const float*)d_in[20];
  float* out = (float*)d_out;

  float* x      = (float*)d_ws;
  float* xn     = x      + (size_t)NN * DIM;
  float* y      = xn     + (size_t)NN * DIM;
  float* agg    = y      + (size_t)NN * DIM;     // also ffn-mid / head buffers
  float* shb    = agg    + (size_t)NN * DIM;
  float* distb  = shb    + (size_t)NE * NSH;
  float* h2b    = distb  + (size_t)NE;
  float* logitsb= h2b    + (size_t)NE * FCH;
  float* alphab = logitsb+ (size_t)NE * NHEAD;
  int* cnt      = (int*)(alphab + (size_t)NE * NHEAD);
  int* row_ptr  = cnt + NN;
  int* csr      = row_ptr + NN + 1;
  int* cursor   = csr + NE;

  dim3 b256(256);
  // geometry
  k_geom<<<(NE+255)/256, b256, 0, stream>>>(pos, esrc, edst, shb, distb);
  // CSR build
  k_zero_int<<<(NN+255)/256, b256, 0, stream>>>(cnt, NN);
  k_count<<<(NE+255)/256, b256, 0, stream>>>(edst, cnt);
  k_scan<<<1, 1024, 0, stream>>>(cnt, row_ptr);
  k_zero_int<<<(NN+255)/256, b256, 0, stream>>>(cursor, NN);
  k_fill<<<(NE+255)/256, b256, 0, stream>>>(edst, row_ptr, cursor, csr);
  // degree embedding + atom embedding -> x
  k_radial<<<(NE+63)/64, b256, 0, stream>>>(distb, deg_w1, deg_w2, h2b);
  k_gather_agg<true><<<2048, 512, 0, stream>>>(row_ptr, csr, esrc, h2b, shb,
      deg_w3, W_deg_sh, nullptr, nullptr, z, atom_emb, x);

  dim3 gemm_grid(79, 8);
  for (int l = 0; l < NL; l++) {
    const float* Wv_l  = Wv  + (size_t)l*DIM*DIM;
    const float* Wsh_l = Wsh + (size_t)l*NSH*DIM;
    const float* w1_l  = rad_w1 + (size_t)l*NBASIS*FCH;
    const float* w2_l  = rad_w2 + (size_t)l*FCH*FCH;
    const float* w3_l  = rad_w3 + (size_t)l*FCH*DIM;
    const float* aa_l  = attn_a + (size_t)l*NHEAD*HDIM;
    const float* Wo_l  = Wo  + (size_t)l*DIM*DIM;
    const float* f1_l  = ffn_w1 + (size_t)l*DIM*DIM;
    const float* f2_l  = ffn_w2 + (size_t)l*DIM*DIM;

    k_ln<<<(NN+3)/4, b256, 0, stream>>>(x, xn, NN, DIM, DIM, DIM);
    k_gemm<0,0><<<gemm_grid, b256, 0, stream>>>(xn, Wv_l, y, NN, DIM, DIM);
    k_radial<<<(NE+63)/64, b256, 0, stream>>>(distb, w1_l, w2_l, h2b);
    k_logits<<<2048, 512, 0, stream>>>(esrc, h2b, shb, w3_l, Wsh_l, aa_l, y, logitsb);
    k_alpha<<<(NN*NHEAD+255)/256, b256, 0, stream>>>(row_ptr, csr, logitsb, alphab);
    k_gather_agg<false><<<2048, 512, 0, stream>>>(row_ptr, csr, esrc, h2b, shb,
        w3_l, Wsh_l, alphab, y, nullptr, nullptr, agg);
    k_gemm<1,0><<<gemm_grid, b256, 0, stream>>>(agg, Wo_l, x, NN, DIM, DIM);   // x += agg@Wo
    k_ln<<<(NN+3)/4, b256, 0, stream>>>(x, xn, NN, DIM, DIM, DIM);
    k_gemm<0,1><<<gemm_grid, b256, 0, stream>>>(xn, f1_l, agg, NN, DIM, DIM);  // mid = silu(xn@W1)
    k_gemm<1,0><<<gemm_grid, b256, 0, stream>>>(agg, f2_l, x, NN, DIM, DIM);   // x += mid@W2
  }

  // output head
  k_ln<<<(NN+3)/4, b256, 0, stream>>>(x, xn, NN, NS, DIM, NS);
  dim3 head_grid(79, 2);
  k_gemm<0,1><<<head_grid, b256, 0, stream>>>(xn, head_w1, y, NN, NS, NS);   // silu(s@w1)
  k_gemm<0,0><<<head_grid, b256, 0, stream>>>(y, head_w2, agg, NN, NS, NS);
  hipMemsetAsync(d_out, 0, (size_t)NG * NS * sizeof(float), stream);
  k_scatter<<<(NN*NS+255)/256, b256, 0, stream>>>(agg, batch, out);
}

// Round 3
// 8552.451 us; speedup vs baseline: 1.0335x; 1.0335x over previous
//
#include <hip/hip_runtime.h>
#include <hip/hip_bf16.h>
#include <math.h>

#define NN 10000
#define NE 160000
#define DIM 480
#define NSH 9
#define NBASIS 128
#define NHEAD 4
#define HDIM 120
#define NL 6
#define NG 256
#define NS 128
#define FCH 64
#define CUTOFF 5.0f

#define CHUNK_TILES 139
#define CHUNK_E (CHUNK_TILES * 128)   // 17792 edges; 9 chunks cover 1250 tiles
#define NCHUNK 9

__device__ __forceinline__ float silu_f(float v) { return v / (1.0f + __expf(-v)); }

struct bf16x4 { __hip_bfloat16 v[4]; };

// ---------------- CSR build ----------------
__global__ void k_zero_int(int* p, int n)
{
  int i = blockIdx.x * 256 + threadIdx.x;
  if (i < n) p[i] = 0;
}

__global__ void k_count(const int* __restrict__ edst, int* __restrict__ cnt)
{
  int e = blockIdx.x * 256 + threadIdx.x;
  if (e < NE) atomicAdd(&cnt[edst[e]], 1);
}

__global__ __launch_bounds__(1024)
void k_scan(const int* __restrict__ cnt, int* __restrict__ row_ptr)
{
  __shared__ int part[1024];
  int tid = threadIdx.x;
  const int per = 10;
  int base = tid * per;
  int s = 0;
  for (int i = 0; i < per; i++) { int idx = base + i; if (idx < NN) s += cnt[idx]; }
  part[tid] = s; __syncthreads();
  for (int off = 1; off < 1024; off <<= 1) {
    int v = (tid >= off) ? part[tid - off] : 0;
    __syncthreads();
    part[tid] += v;
    __syncthreads();
  }
  int run = (tid > 0) ? part[tid - 1] : 0;
  for (int i = 0; i < per; i++) {
    int idx = base + i;
    if (idx < NN) { row_ptr[idx] = run; run += cnt[idx]; }
  }
  if (tid == 1023) row_ptr[NN] = part[1023];
}

__global__ void k_fill(const int* __restrict__ edst, const int* __restrict__ row_ptr,
                       int* __restrict__ cursor, int* __restrict__ csr)
{
  int e = blockIdx.x * 256 + threadIdx.x;
  if (e >= NE) return;
  int d = edst[e];
  int p = atomicAdd(&cursor[d], 1);
  csr[row_ptr[d] + p] = e;
}

// ---------------- geometry in permuted (CSR) order ----------------
__global__ void k_geom_p(const float* __restrict__ pos, const int* __restrict__ esrc,
                         const int* __restrict__ edst, const int* __restrict__ csr,
                         float* __restrict__ shp, float* __restrict__ distp,
                         int* __restrict__ esrcp)
{
  int j = blockIdx.x * 256 + threadIdx.x;
  if (j >= NE) return;
  int e = csr[j];
  int s = esrc[e], d = edst[e];
  esrcp[j] = s;
  float vx = pos[s*3+0] - pos[d*3+0];
  float vy = pos[s*3+1] - pos[d*3+1];
  float vz = pos[s*3+2] - pos[d*3+2];
  float r = sqrtf(vx*vx + vy*vy + vz*vz);
  distp[j] = r;
  float inv = 1.0f / (r + 1e-9f);
  float x = vx*inv, y = vy*inv, z = vz*inv;
  const float s3 = 1.7320508075688772f;
  const float s15 = 3.872983346207417f;
  const float s5 = 2.23606797749979f;
  float* o = shp + (size_t)j * NSH;
  o[0] = 1.0f;
  o[1] = s3*x; o[2] = s3*y; o[3] = s3*z;
  o[4] = s15*x*y; o[5] = s15*y*z; o[6] = 0.5f*s5*(3.0f*z*z - 1.0f);
  o[7] = s15*x*z; o[8] = 0.5f*s15*(x*x - y*y);
}

// ---------------- radial MLP (rb -> silu -> silu), h2 out [E,64] ----------------
__global__ __launch_bounds__(256)
void k_radial(const float* __restrict__ dist, const float* __restrict__ w1,
              const float* __restrict__ w2, float* __restrict__ h2out)
{
  __shared__ float rbs[NBASIS][65];
  __shared__ float wsm[NBASIS * FCH];
  __shared__ float ds[64];
  int tid = threadIdx.x;
  int e0 = blockIdx.x * 64;
  if (tid < 64) {
    int e = e0 + tid;
    ds[tid] = (e < NE) ? dist[e] : 1e9f;
  }
  for (int i = tid; i < NBASIS * FCH; i += 256) wsm[i] = w1[i];
  __syncthreads();
  const float invw = (float)NBASIS / CUTOFF;
  for (int i = tid; i < NBASIS * 64; i += 256) {
    int k = i >> 6, e = i & 63;
    float c = k * (CUTOFF / 127.0f);
    float tt = (ds[e] - c) * invw;
    rbs[k][e] = __expf(-0.5f * tt * tt);
  }
  __syncthreads();
  int ty = tid >> 4, tx = tid & 15;
  float acc1[4][4] = {};
  for (int k = 0; k < NBASIS; k++) {
    float b[4];
#pragma unroll
    for (int j = 0; j < 4; j++) b[j] = wsm[k*FCH + tx*4 + j];
#pragma unroll
    for (int i = 0; i < 4; i++) {
      float a = rbs[k][ty*4 + i];
#pragma unroll
      for (int j = 0; j < 4; j++) acc1[i][j] = fmaf(a, b[j], acc1[i][j]);
    }
  }
  __syncthreads();
#pragma unroll
  for (int i = 0; i < 4; i++)
#pragma unroll
    for (int j = 0; j < 4; j++)
      rbs[tx*4 + j][ty*4 + i] = silu_f(acc1[i][j]);
  for (int i = tid; i < FCH * FCH; i += 256) wsm[i] = w2[i];
  __syncthreads();
  float acc2[4][4] = {};
  for (int k = 0; k < FCH; k++) {
    float b[4];
#pragma unroll
    for (int j = 0; j < 4; j++) b[j] = wsm[k*FCH + tx*4 + j];
#pragma unroll
    for (int i = 0; i < 4; i++) {
      float a = rbs[k][ty*4 + i];
#pragma unroll
      for (int j = 0; j < 4; j++) acc2[i][j] = fmaf(a, b[j], acc2[i][j]);
    }
  }
#pragma unroll
  for (int i = 0; i < 4; i++) {
    int e = e0 + ty*4 + i;
    if (e >= NE) continue;
#pragma unroll
    for (int j = 0; j < 4; j++)
      h2out[(size_t)e*FCH + tx*4 + j] = silu_f(acc2[i][j]);
  }
}

// ---------------- layernorm ----------------
__global__ __launch_bounds__(256)
void k_ln(const float* __restrict__ in, float* __restrict__ out,
          int n, int cols, int in_stride, int out_stride)
{
  int wave = blockIdx.x * 4 + (threadIdx.x >> 6);
  int lane = threadIdx.x & 63;
  if (wave >= n) return;
  const float* r = in + (size_t)wave * in_stride;
  float s = 0.f, ss = 0.f;
  for (int c = lane; c < cols; c += 64) { float v = r[c]; s += v; ss += v*v; }
  for (int off = 32; off > 0; off >>= 1) { s += __shfl_down(s, off); ss += __shfl_down(ss, off); }
  s = __shfl(s, 0); ss = __shfl(ss, 0);
  float mu = s / cols;
  float var = ss / cols - mu * mu;
  float rstd = rsqrtf(fmaxf(var, 0.f) + 1e-5f);
  float* o = out + (size_t)wave * out_stride;
  for (int c = lane; c < cols; c += 64) o[c] = (r[c] - mu) * rstd;
}

// ---------------- tiled f32 GEMM: 128x128 tile, 8x8 microtile (split cols) ----------------
template<int ADD, int SILU>
__global__ __launch_bounds__(256)
void k_gemm(const float* __restrict__ A, const float* __restrict__ B,
            float* __restrict__ C, int M, int K, int Nc)
{
  __shared__ float As[16][132];   // [k][row]
  __shared__ float Bs[16][128];   // [k][col]
  int tid = threadIdx.x;
  int ty = tid >> 4, tx = tid & 15;
  int row0 = blockIdx.x * 128;
  int col0 = blockIdx.y * 128;
  float acc[8][8] = {};
  for (int k0 = 0; k0 < K; k0 += 16) {
    __syncthreads();
#pragma unroll
    for (int c = tid; c < 512; c += 256) {
      int r = c >> 2, kq = c & 3;
      int grow = row0 + r;
      float4 v = make_float4(0.f,0.f,0.f,0.f);
      if (grow < M) v = *(const float4*)(A + (size_t)grow * K + k0 + kq*4);
      As[kq*4+0][r] = v.x; As[kq*4+1][r] = v.y; As[kq*4+2][r] = v.z; As[kq*4+3][r] = v.w;
    }
#pragma unroll
    for (int c = tid; c < 512; c += 256) {
      int kk = c >> 5, cq = c & 31;
      int col = col0 + cq*4;
      float4 v = make_float4(0.f,0.f,0.f,0.f);
      if (col < Nc) v = *(const float4*)(B + (size_t)(k0+kk) * Nc + col);
      *(float4*)&Bs[kk][cq*4] = v;
    }
    __syncthreads();
#pragma unroll
    for (int kk = 0; kk < 16; kk++) {
      float4 a0 = *(const float4*)&As[kk][ty*8];
      float4 a1 = *(const float4*)&As[kk][ty*8+4];
      float4 b0 = *(const float4*)&Bs[kk][tx*4];
      float4 b1 = *(const float4*)&Bs[kk][64 + tx*4];
      float a[8] = {a0.x,a0.y,a0.z,a0.w,a1.x,a1.y,a1.z,a1.w};
      float b[8] = {b0.x,b0.y,b0.z,b0.w,b1.x,b1.y,b1.z,b1.w};
#pragma unroll
      for (int i = 0; i < 8; i++)
#pragma unroll
        for (int j = 0; j < 8; j++) acc[i][j] = fmaf(a[i], b[j], acc[i][j]);
    }
  }
#pragma unroll
  for (int i = 0; i < 8; i++) {
    int row = row0 + ty*8 + i;
    if (row >= M) continue;
#pragma unroll
    for (int j = 0; j < 8; j++) {
      int col = col0 + ((j < 4) ? (tx*4 + j) : (64 + tx*4 + j - 4));
      if (col >= Nc) continue;
      float v = acc[i][j];
      if (SILU) v = silu_f(v);
      float* p = C + (size_t)row * Nc + col;
      if (ADD) *p += v; else *p = v;
    }
  }
}

// ---------------- msg GEMM passes ----------------
// MODE 0: logits only (attn pass A).  MODE 1: alpha-weighted msg store (attn pass B).
// MODE 2: unweighted msg store (degree embedding).
// tile: 128 edges x 128 cols, K=64 (BK=32), 8x8 microtile (split cols tx*4 / 64+tx*4)
template<int MODE>
__global__ __launch_bounds__(256)
void k_msg(const float* __restrict__ h2, const float* __restrict__ shp,
           const int* __restrict__ esrcp, const float* __restrict__ w3,
           const float* __restrict__ wsh, const float* __restrict__ aa,
           const float* __restrict__ y, const float* __restrict__ alpha,
           int jbeg, int jend,
           __hip_bfloat16* __restrict__ msgc, float* __restrict__ logits)
{
  int e0 = jbeg + blockIdx.x * 128;
  if (e0 >= jend) return;                   // uniform exit (tail chunk)
  __shared__ float h2s[32][132];
  __shared__ float w3s[32][128];
  __shared__ float shs[128][9];
  __shared__ float wshs[9][128];
  __shared__ float aas[128];
  __shared__ float als[128][4];
  __shared__ int   srcs[128];
  int tid = threadIdx.x;
  int ty = tid >> 4, tx = tid & 15;
  int col0 = blockIdx.y * 128;
  for (int idx = tid; idx < 128*9; idx += 256) {
    int r = idx / 9, q = idx - r*9;
    shs[r][q] = shp[(size_t)(e0+r)*NSH + q];
  }
  for (int idx = tid; idx < 9*32; idx += 256) {
    int q = idx >> 5, cq = idx & 31;
    int col = col0 + cq*4;
    float4 v = make_float4(0.f,0.f,0.f,0.f);
    if (col < DIM) v = *(const float4*)(wsh + (size_t)q*DIM + col);
    *(float4*)&wshs[q][cq*4] = v;
  }
  if (tid < 128) {
    int col = col0 + tid;
    aas[tid] = (MODE == 0 && col < DIM) ? aa[col] : 0.f;
    srcs[tid] = esrcp[e0 + tid];
    if (MODE == 1)
      *(float4*)&als[tid][0] = *(const float4*)(alpha + (size_t)(e0+tid)*NHEAD);
  }
  float acc[8][8] = {};
  for (int k0 = 0; k0 < FCH; k0 += 32) {
    __syncthreads();
    for (int idx = tid; idx < 1024; idx += 256) {   // h2 tile transposed
      int el = idx >> 3, kq = idx & 7;
      float4 v = *(const float4*)(h2 + (size_t)(e0+el)*FCH + k0 + kq*4);
      h2s[kq*4+0][el] = v.x; h2s[kq*4+1][el] = v.y; h2s[kq*4+2][el] = v.z; h2s[kq*4+3][el] = v.w;
    }
    for (int idx = tid; idx < 1024; idx += 256) {   // w3 slice
      int kk = idx >> 5, cq = idx & 31;
      int col = col0 + cq*4;
      float4 v = make_float4(0.f,0.f,0.f,0.f);
      if (col < DIM) v = *(const float4*)(w3 + (size_t)(k0+kk)*DIM + col);
      *(float4*)&w3s[kk][cq*4] = v;
    }
    __syncthreads();
#pragma unroll
    for (int kk = 0; kk < 32; kk++) {
      float4 a0 = *(const float4*)&h2s[kk][ty*8];
      float4 a1 = *(const float4*)&h2s[kk][ty*8+4];
      float4 b0 = *(const float4*)&w3s[kk][tx*4];
      float4 b1 = *(const float4*)&w3s[kk][64 + tx*4];
      float a[8] = {a0.x,a0.y,a0.z,a0.w,a1.x,a1.y,a1.z,a1.w};
      float b[8] = {b0.x,b0.y,b0.z,b0.w,b1.x,b1.y,b1.z,b1.w};
#pragma unroll
      for (int i = 0; i < 8; i++)
#pragma unroll
        for (int j = 0; j < 8; j++) acc[i][j] = fmaf(a[i], b[j], acc[i][j]);
    }
  }
  // epilogue
  int headA = col0 / 120;
  bool validB = (col0 + 64 + tx*4 + 3) < DIM;
  int headG0 = (col0 + tx*4) / 120;
  int headG1 = validB ? ((col0 + 64 + tx*4) / 120) : headA;
#pragma unroll
  for (int i = 0; i < 8; i++) {
    int el = ty*8 + i;
    int row = e0 + el;
    float sw[8];
#pragma unroll
    for (int j = 0; j < 8; j++) sw[j] = 0.f;
#pragma unroll
    for (int q = 0; q < 9; q++) {
      float shq = shs[el][q];
#pragma unroll
      for (int j = 0; j < 4; j++) {
        sw[j]   = fmaf(shq, wshs[q][tx*4 + j], sw[j]);
        sw[4+j] = fmaf(shq, wshs[q][64 + tx*4 + j], sw[4+j]);
      }
    }
    float vj[8];
    if (MODE == 2) {
#pragma unroll
      for (int j = 0; j < 8; j++) vj[j] = 1.f;
    } else {
      const float* yr = y + (size_t)srcs[el]*DIM;
      float4 y0 = *(const float4*)(yr + col0 + tx*4);
      vj[0]=y0.x; vj[1]=y0.y; vj[2]=y0.z; vj[3]=y0.w;
      if (validB) {
        float4 y1 = *(const float4*)(yr + col0 + 64 + tx*4);
        vj[4]=y1.x; vj[5]=y1.y; vj[6]=y1.z; vj[7]=y1.w;
      } else { vj[4]=vj[5]=vj[6]=vj[7]=0.f; }
    }
    float m[8];
#pragma unroll
    for (int j = 0; j < 8; j++) m[j] = vj[j] * sw[j] * acc[i][j];

    if (MODE == 0) {
      float p0 = 0.f, p1 = 0.f;
#pragma unroll
      for (int j = 0; j < 4; j++) {
        float l0 = (m[j]   > 0.f) ? m[j]   : 0.2f*m[j];
        float l1 = (m[4+j] > 0.f) ? m[4+j] : 0.2f*m[4+j];
        p0 = fmaf(l0, aas[tx*4 + j], p0);
        p1 = fmaf(l1, aas[64 + tx*4 + j], p1);
      }
      float pA = (headG0 == headA) ? p0 : 0.f;
      float pB = (headG0 == headA) ? 0.f : p0;
      pA += (headG1 == headA) ? p1 : 0.f;
      pB += (headG1 == headA) ? 0.f : p1;
#pragma unroll
      for (int off = 8; off > 0; off >>= 1) {
        pA += __shfl_down(pA, off, 16);
        pB += __shfl_down(pB, off, 16);
      }
      if (tx == 0) {
        atomicAdd(&logits[(size_t)row*NHEAD + headA], pA);
        if (headA < 3 && (headA+1)*120 < col0 + 128)
          atomicAdd(&logits[(size_t)row*NHEAD + headA + 1], pB);
      }
    } else {
      if (MODE == 1) {
        float a0 = als[el][headG0];
        float a1 = als[el][headG1];
#pragma unroll
        for (int j = 0; j < 4; j++) { m[j] *= a0; m[4+j] *= a1; }
      }
      __hip_bfloat16* mr = msgc + (size_t)(row - jbeg)*DIM;
      bf16x4 pa;
#pragma unroll
      for (int j = 0; j < 4; j++) pa.v[j] = __float2bfloat16(m[j]);
      *(bf16x4*)(mr + col0 + tx*4) = pa;
      if (validB) {
        bf16x4 pb;
#pragma unroll
        for (int j = 0; j < 4; j++) pb.v[j] = __float2bfloat16(m[4+j]);
        *(bf16x4*)(mr + col0 + 64 + tx*4) = pb;
      }
    }
  }
}

// ---------------- segment softmax ----------------
__global__ void k_alpha(const int* __restrict__ row_ptr, const float* __restrict__ logits,
                        float* __restrict__ alpha)
{
  int i = blockIdx.x * 256 + threadIdx.x;
  if (i >= NN * NHEAD) return;
  int d = i >> 2, h = i & 3;
  int beg = row_ptr[d], end = row_ptr[d+1];
  if (beg == end) return;
  float m = -1e30f;
  for (int j = beg; j < end; j++) m = fmaxf(m, logits[(size_t)j*NHEAD + h]);
  float s = 0.f;
  for (int j = beg; j < end; j++) {
    float ex = __expf(logits[(size_t)j*NHEAD + h] - m);
    alpha[(size_t)j*NHEAD + h] = ex;
    s += ex;
  }
  float inv = 1.f / (s + 1e-9f);
  for (int j = beg; j < end; j++) alpha[(size_t)j*NHEAD + h] *= inv;
}

// ---------------- chunked segmented sum: outx[d] += scale * sum_j msg[j] ----------------
__global__ __launch_bounds__(512)
void k_agg(const int* __restrict__ row_ptr, const __hip_bfloat16* __restrict__ chunk,
           int jbeg, int jend, float* __restrict__ outx, float scale)
{
  int d = blockIdx.x;
  int t = threadIdx.x;
  int beg = row_ptr[d], end = row_ptr[d+1];
  if (beg < jbeg) beg = jbeg;
  if (end > jend) end = jend;
  if (beg >= end || t >= DIM) return;
  float acc = 0.f;
  for (int j = beg; j < end; j++)
    acc += __bfloat162float(chunk[(size_t)(j - jbeg)*DIM + t]);
  outx[(size_t)d*DIM + t] += scale * acc;
}

// ---------------- x init: atom embedding gather ----------------
__global__ void k_init_x(const int* __restrict__ z, const float* __restrict__ emb,
                         float* __restrict__ x)
{
  int i = blockIdx.x * 256 + threadIdx.x;
  if (i >= NN * DIM) return;
  int n = i / DIM, c = i - n * DIM;
  x[i] = emb[(size_t)z[n]*DIM + c];
}

// ---------------- final scatter over molecules ----------------
__global__ void k_scatter(const float* __restrict__ h, const int* __restrict__ batch,
                          float* __restrict__ out)
{
  int i = blockIdx.x * 256 + threadIdx.x;
  if (i >= NN * NS) return;
  int n = i >> 7;
  atomicAdd(&out[(size_t)batch[n]*NS + (i & 127)], h[i] * 0.23570226039551584f);
}

extern "C" void kernel_launch(void* const* d_in, const int* in_sizes, int n_in,
                              void* d_out, int out_size, void* d_ws, size_t ws_size,
                              hipStream_t stream)
{
  const int*   z        = (const int*)  d_in[0];
  const float* pos      = (const float*)d_in[1];
  const int*   batch    = (const int*)  d_in[2];
  const int*   esrc     = (const int*)  d_in[3];
  const int*   edst     = (const int*)  d_in[4];
  const float* atom_emb = (const float*)d_in[5];
  const float* W_deg_sh = (const float*)d_in[6];
  const float* deg_w1   = (const float*)d_in[7];
  const float* deg_w2   = (const float*)d_in[8];
  const float* deg_w3   = (const float*)d_in[9];
  const float* Wv       = (const float*)d_in[10];
  const float* Wsh      = (const float*)d_in[11];
  const float* rad_w1   = (const float*)d_in[12];
  const float* rad_w2   = (const float*)d_in[13];
  const float* rad_w3   = (const float*)d_in[14];
  const float* attn_a   = (const float*)d_in[15];
  const float* Wo       = (const float*)d_in[16];
  const float* ffn_w1   = (const float*)d_in[17];
  const float* ffn_w2   = (const float*)d_in[18];
  const float* head_w1  = (const float*)d_in[19];
  const float* head_w2  = (const float*)d_in[20];
  float* out = (float*)d_out;

  // workspace layout (total ~130.7 MB, same as round-1 proven size)
  float* x      = (float*)d_ws;
  float* xn     = x      + (size_t)NN * DIM;     // doubles as msg chunk buffer
  float* y      = xn     + (size_t)NN * DIM;
  float* agg    = y      + (size_t)NN * DIM;
  float* shp    = agg    + (size_t)NN * DIM;
  float* distp  = shp    + (size_t)NE * NSH;
  float* h2b    = distp  + (size_t)NE;
  float* logitsb= h2b    + (size_t)NE * FCH;
  float* alphab = logitsb+ (size_t)NE * NHEAD;
  int* cnt      = (int*)(alphab + (size_t)NE * NHEAD);
  int* row_ptr  = cnt + NN;
  int* csr      = row_ptr + NN + 1;
  int* cursor   = csr + NE;
  int* esrcp    = cursor + NN;
  __hip_bfloat16* msgc = (__hip_bfloat16*)xn;    // 17792*480*2B = 17.1MB <= 19.2MB

  dim3 b256(256);
  // CSR build (dst-sorted edge permutation)
  k_zero_int<<<(NN+255)/256, b256, 0, stream>>>(cnt, NN);
  k_count<<<(NE+255)/256, b256, 0, stream>>>(edst, cnt);
  k_scan<<<1, 1024, 0, stream>>>(cnt, row_ptr);
  k_zero_int<<<(NN+255)/256, b256, 0, stream>>>(cursor, NN);
  k_fill<<<(NE+255)/256, b256, 0, stream>>>(edst, row_ptr, cursor, csr);
  k_geom_p<<<(NE+255)/256, b256, 0, stream>>>(pos, esrc, edst, csr, shp, distp, esrcp);

  // degree embedding: x = emb[z] + (1/16) * segsum(sw * gate)
  k_radial<<<NE/64, b256, 0, stream>>>(distp, deg_w1, deg_w2, h2b);
  k_init_x<<<(NN*DIM+255)/256, b256, 0, stream>>>(z, atom_emb, x);
  for (int c = 0; c < NCHUNK; c++) {
    int jbeg = c * CHUNK_E;
    int jend = (jbeg + CHUNK_E < NE) ? jbeg + CHUNK_E : NE;
    dim3 mg((jend - jbeg + 127)/128, 4);
    k_msg<2><<<mg, b256, 0, stream>>>(h2b, shp, esrcp, deg_w3, W_deg_sh,
        nullptr, nullptr, nullptr, jbeg, jend, msgc, nullptr);
    k_agg<<<NN, 512, 0, stream>>>(row_ptr, msgc, jbeg, jend, x, 1.0f/16.0f);
  }

  dim3 gemm_grid(79, 4);
  dim3 msgA_grid(NE/128, 4);
  for (int l = 0; l < NL; l++) {
    const float* Wv_l  = Wv  + (size_t)l*DIM*DIM;
    const float* Wsh_l = Wsh + (size_t)l*NSH*DIM;
    const float* w1_l  = rad_w1 + (size_t)l*NBASIS*FCH;
    const float* w2_l  = rad_w2 + (size_t)l*FCH*FCH;
    const float* w3_l  = rad_w3 + (size_t)l*FCH*DIM;
    const float* aa_l  = attn_a + (size_t)l*NHEAD*HDIM;
    const float* Wo_l  = Wo  + (size_t)l*DIM*DIM;
    const float* f1_l  = ffn_w1 + (size_t)l*DIM*DIM;
    const float* f2_l  = ffn_w2 + (size_t)l*DIM*DIM;

    k_ln<<<(NN+3)/4, b256, 0, stream>>>(x, xn, NN, DIM, DIM, DIM);
    k_gemm<0,0><<<gemm_grid, b256, 0, stream>>>(xn, Wv_l, y, NN, DIM, DIM);  // xn dead after
    k_radial<<<NE/64, b256, 0, stream>>>(distp, w1_l, w2_l, h2b);
    hipMemsetAsync(logitsb, 0, (size_t)NE * NHEAD * sizeof(float), stream);
    k_msg<0><<<msgA_grid, b256, 0, stream>>>(h2b, shp, esrcp, w3_l, Wsh_l,
        aa_l, y, nullptr, 0, NE, nullptr, logitsb);
    k_alpha<<<(NN*NHEAD+255)/256, b256, 0, stream>>>(row_ptr, logitsb, alphab);
    hipMemsetAsync(agg, 0, (size_t)NN * DIM * sizeof(float), stream);
    for (int c = 0; c < NCHUNK; c++) {
      int jbeg = c * CHUNK_E;
      int jend = (jbeg + CHUNK_E < NE) ? jbeg + CHUNK_E : NE;
      dim3 mg((jend - jbeg + 127)/128, 4);
      k_msg<1><<<mg, b256, 0, stream>>>(h2b, shp, esrcp, w3_l, Wsh_l,
          nullptr, y, alphab, jbeg, jend, msgc, nullptr);
      k_agg<<<NN, 512, 0, stream>>>(row_ptr, msgc, jbeg, jend, agg, 1.0f);
    }
    k_gemm<1,0><<<gemm_grid, b256, 0, stream>>>(agg, Wo_l, x, NN, DIM, DIM);
    k_ln<<<(NN+3)/4, b256, 0, stream>>>(x, xn, NN, DIM, DIM, DIM);
    k_gemm<0,1><<<gemm_grid, b256, 0, stream>>>(xn, f1_l, agg, NN, DIM, DIM);
    k_gemm<1,0><<<gemm_grid, b256, 0, stream>>>(agg, f2_l, x, NN, DIM, DIM);
  }

  // output head
  k_ln<<<(NN+3)/4, b256, 0, stream>>>(x, xn, NN, NS, DIM, NS);
  dim3 head_grid(79, 1);
  k_gemm<0,1><<<head_grid, b256, 0, stream>>>(xn, head_w1, y, NN, NS, NS);
  k_gemm<0,0><<<head_grid, b256, 0, stream>>>(y, head_w2, agg, NN, NS, NS);
  hipMemsetAsync(d_out, 0, (size_t)NG * NS * sizeof(float), stream);
  k_scatter<<<(NN*NS+255)/256, b256, 0, stream>>>(agg, batch, out);
}

// Round 4
// 6896.986 us; speedup vs baseline: 1.2816x; 1.2400x over previous
//
#include <hip/hip_runtime.h>
#include <hip/hip_bf16.h>
#include <math.h>

#define NN 10000
#define NE 160000
#define DIM 480
#define NSH 9
#define NBASIS 128
#define NHEAD 4
#define HDIM 120
#define NL 6
#define NG 256
#define NS 128
#define FCH 64
#define CUTOFF 5.0f

__device__ __forceinline__ float silu_f(float v) { return v / (1.0f + __expf(-v)); }
__device__ __forceinline__ float bf2f(ushort u) { return __uint_as_float(((unsigned)u) << 16); }

struct bf16x4 { __hip_bfloat16 v[4]; };

// ---------------- CSR build ----------------
__global__ void k_zero_int(int* p, int n)
{
  int i = blockIdx.x * 256 + threadIdx.x;
  if (i < n) p[i] = 0;
}

__global__ void k_count(const int* __restrict__ edst, int* __restrict__ cnt)
{
  int e = blockIdx.x * 256 + threadIdx.x;
  if (e < NE) atomicAdd(&cnt[edst[e]], 1);
}

__global__ __launch_bounds__(1024)
void k_scan(const int* __restrict__ cnt, int* __restrict__ row_ptr)
{
  __shared__ int part[1024];
  int tid = threadIdx.x;
  const int per = 10;
  int base = tid * per;
  int s = 0;
  for (int i = 0; i < per; i++) { int idx = base + i; if (idx < NN) s += cnt[idx]; }
  part[tid] = s; __syncthreads();
  for (int off = 1; off < 1024; off <<= 1) {
    int v = (tid >= off) ? part[tid - off] : 0;
    __syncthreads();
    part[tid] += v;
    __syncthreads();
  }
  int run = (tid > 0) ? part[tid - 1] : 0;
  for (int i = 0; i < per; i++) {
    int idx = base + i;
    if (idx < NN) { row_ptr[idx] = run; run += cnt[idx]; }
  }
  if (tid == 1023) row_ptr[NN] = part[1023];
}

__global__ void k_fill(const int* __restrict__ edst, const int* __restrict__ row_ptr,
                       int* __restrict__ cursor, int* __restrict__ csr)
{
  int e = blockIdx.x * 256 + threadIdx.x;
  if (e >= NE) return;
  int d = edst[e];
  int p = atomicAdd(&cursor[d], 1);
  csr[row_ptr[d] + p] = e;
}

// ---------------- geometry in permuted (CSR) order ----------------
__global__ void k_geom_p(const float* __restrict__ pos, const int* __restrict__ esrc,
                         const int* __restrict__ edst, const int* __restrict__ csr,
                         float* __restrict__ shp, float* __restrict__ distp,
                         int* __restrict__ esrcp, int* __restrict__ edstp)
{
  int j = blockIdx.x * 256 + threadIdx.x;
  if (j >= NE) return;
  int e = csr[j];
  int s = esrc[e], d = edst[e];
  esrcp[j] = s;
  edstp[j] = d;
  float vx = pos[s*3+0] - pos[d*3+0];
  float vy = pos[s*3+1] - pos[d*3+1];
  float vz = pos[s*3+2] - pos[d*3+2];
  float r = sqrtf(vx*vx + vy*vy + vz*vz);
  distp[j] = r;
  float inv = 1.0f / (r + 1e-9f);
  float x = vx*inv, y = vy*inv, z = vz*inv;
  const float s3 = 1.7320508075688772f;
  const float s15 = 3.872983346207417f;
  const float s5 = 2.23606797749979f;
  float* o = shp + (size_t)j * NSH;
  o[0] = 1.0f;
  o[1] = s3*x; o[2] = s3*y; o[3] = s3*z;
  o[4] = s15*x*y; o[5] = s15*y*z; o[6] = 0.5f*s5*(3.0f*z*z - 1.0f);
  o[7] = s15*x*z; o[8] = 0.5f*s15*(x*x - y*y);
}

// ---------------- radial MLP -> h2 bf16 [E,64] ----------------
__global__ __launch_bounds__(256)
void k_radial(const float* __restrict__ dist, const float* __restrict__ w1,
              const float* __restrict__ w2, __hip_bfloat16* __restrict__ h2out)
{
  __shared__ float rbs[NBASIS][65];
  __shared__ float wsm[NBASIS * FCH];
  __shared__ float ds[64];
  int tid = threadIdx.x;
  int e0 = blockIdx.x * 64;
  if (tid < 64) ds[tid] = dist[e0 + tid];
  for (int i = tid; i < NBASIS * FCH; i += 256) wsm[i] = w1[i];
  __syncthreads();
  const float invw = (float)NBASIS / CUTOFF;
  for (int i = tid; i < NBASIS * 64; i += 256) {
    int k = i >> 6, e = i & 63;
    float c = k * (CUTOFF / 127.0f);
    float tt = (ds[e] - c) * invw;
    rbs[k][e] = __expf(-0.5f * tt * tt);
  }
  __syncthreads();
  int ty = tid >> 4, tx = tid & 15;
  float acc1[4][4] = {};
  for (int k = 0; k < NBASIS; k++) {
    float b[4];
#pragma unroll
    for (int j = 0; j < 4; j++) b[j] = wsm[k*FCH + tx*4 + j];
#pragma unroll
    for (int i = 0; i < 4; i++) {
      float a = rbs[k][ty*4 + i];
#pragma unroll
      for (int j = 0; j < 4; j++) acc1[i][j] = fmaf(a, b[j], acc1[i][j]);
    }
  }
  __syncthreads();
#pragma unroll
  for (int i = 0; i < 4; i++)
#pragma unroll
    for (int j = 0; j < 4; j++)
      rbs[tx*4 + j][ty*4 + i] = silu_f(acc1[i][j]);
  for (int i = tid; i < FCH * FCH; i += 256) wsm[i] = w2[i];
  __syncthreads();
  float acc2[4][4] = {};
  for (int k = 0; k < FCH; k++) {
    float b[4];
#pragma unroll
    for (int j = 0; j < 4; j++) b[j] = wsm[k*FCH + tx*4 + j];
#pragma unroll
    for (int i = 0; i < 4; i++) {
      float a = rbs[k][ty*4 + i];
#pragma unroll
      for (int j = 0; j < 4; j++) acc2[i][j] = fmaf(a, b[j], acc2[i][j]);
    }
  }
#pragma unroll
  for (int i = 0; i < 4; i++) {
    int e = e0 + ty*4 + i;
    bf16x4 p;
#pragma unroll
    for (int j = 0; j < 4; j++) p.v[j] = __float2bfloat16(silu_f(acc2[i][j]));
    *(bf16x4*)(h2out + (size_t)e*FCH + tx*4) = p;
  }
}

// ---------------- per-row LN stats (mu, rstd) ----------------
__global__ __launch_bounds__(256)
void k_stats(const float* __restrict__ in, float* __restrict__ st,
             int n, int cols, int stride)
{
  int row = blockIdx.x * 4 + (threadIdx.x >> 6);
  int lane = threadIdx.x & 63;
  if (row >= n) return;
  const float* r = in + (size_t)row * stride;
  float s = 0.f, ss = 0.f;
  for (int c = lane; c < cols; c += 64) { float v = r[c]; s += v; ss += v*v; }
  for (int off = 32; off > 0; off >>= 1) { s += __shfl_down(s, off); ss += __shfl_down(ss, off); }
  if (lane == 0) {
    float mu = s / cols;
    float var = ss / cols - mu * mu;
    st[row*2]   = mu;
    st[row*2+1] = rsqrtf(fmaxf(var, 0.f) + 1e-5f);
  }
}

// ---------------- tiled f32 GEMM: C = (silu?)((LN?)A @ B), optional +=, optional bf16 out ----
template<int ADD, int SILU, int LNA, int OBF16>
__global__ __launch_bounds__(256)
void k_gemm(const float* __restrict__ A, const float* __restrict__ B,
            float* __restrict__ C, __hip_bfloat16* __restrict__ Cb,
            const float* __restrict__ st, int M, int K, int Nc, int lda)
{
  __shared__ float As[16][132];
  __shared__ float Bs[16][128];
  __shared__ float smu[128], srs[128];
  int tid = threadIdx.x;
  int ty = tid >> 4, tx = tid & 15;
  int row0 = blockIdx.x * 128;
  int col0 = blockIdx.y * 128;
  if (LNA && tid < 128) {
    int gr = row0 + tid;
    float m2 = 0.f, r2 = 1.f;
    if (gr < M) { m2 = st[gr*2]; r2 = st[gr*2+1]; }
    smu[tid] = m2; srs[tid] = r2;
  }
  float acc[8][8] = {};
  for (int k0 = 0; k0 < K; k0 += 16) {
    __syncthreads();
#pragma unroll
    for (int c = tid; c < 512; c += 256) {
      int r = c >> 2, kq = c & 3;
      int grow = row0 + r;
      float4 v = make_float4(0.f,0.f,0.f,0.f);
      if (grow < M) v = *(const float4*)(A + (size_t)grow * lda + k0 + kq*4);
      if (LNA) {
        float mu = smu[r], rs = srs[r];
        v.x = (v.x - mu) * rs; v.y = (v.y - mu) * rs;
        v.z = (v.z - mu) * rs; v.w = (v.w - mu) * rs;
      }
      As[kq*4+0][r] = v.x; As[kq*4+1][r] = v.y; As[kq*4+2][r] = v.z; As[kq*4+3][r] = v.w;
    }
#pragma unroll
    for (int c = tid; c < 512; c += 256) {
      int kk = c >> 5, cq = c & 31;
      int col = col0 + cq*4;
      float4 v = make_float4(0.f,0.f,0.f,0.f);
      if (col < Nc) v = *(const float4*)(B + (size_t)(k0+kk) * Nc + col);
      *(float4*)&Bs[kk][cq*4] = v;
    }
    __syncthreads();
#pragma unroll
    for (int kk = 0; kk < 16; kk++) {
      float4 a0 = *(const float4*)&As[kk][ty*8];
      float4 a1 = *(const float4*)&As[kk][ty*8+4];
      float4 b0 = *(const float4*)&Bs[kk][tx*4];
      float4 b1 = *(const float4*)&Bs[kk][64 + tx*4];
      float a[8] = {a0.x,a0.y,a0.z,a0.w,a1.x,a1.y,a1.z,a1.w};
      float b[8] = {b0.x,b0.y,b0.z,b0.w,b1.x,b1.y,b1.z,b1.w};
#pragma unroll
      for (int i = 0; i < 8; i++)
#pragma unroll
        for (int j = 0; j < 8; j++) acc[i][j] = fmaf(a[i], b[j], acc[i][j]);
    }
  }
#pragma unroll
  for (int i = 0; i < 8; i++) {
    int row = row0 + ty*8 + i;
    if (row >= M) continue;
#pragma unroll
    for (int j = 0; j < 8; j++) {
      int col = col0 + ((j < 4) ? (tx*4 + j) : (64 + tx*4 + j - 4));
      if (col >= Nc) continue;
      float v = acc[i][j];
      if (SILU) v = silu_f(v);
      if (OBF16) Cb[(size_t)row * Nc + col] = __float2bfloat16(v);
      else {
        float* p = C + (size_t)row * Nc + col;
        if (ADD) *p += v; else *p = v;
      }
    }
  }
}

// ---------------- msg GEMM with fused epilogue ----------------
// MODE 0: logits (leaky(m).aa per head, atomic).  MODE 1: alpha-weighted per-dst
// run-reduction -> atomicAdd agg.  MODE 2: unweighted (scale 1/16) -> atomicAdd x.
// tile: 128 CSR-edges x 128 cols; K=64 staged in 2x32; 8x8 microtile (split cols).
template<int MODE>
__global__ __launch_bounds__(256)
void k_msg(const __hip_bfloat16* __restrict__ h2, const float* __restrict__ shp,
           const int* __restrict__ esrcp, const int* __restrict__ edstp,
           const float* __restrict__ w3, const float* __restrict__ wsh,
           const float* __restrict__ aa, const __hip_bfloat16* __restrict__ y,
           const float* __restrict__ alpha, float* __restrict__ outbuf)
{
  __shared__ float h2s[32][132];
  __shared__ float w3s[32][128];
  __shared__ float shs[128][10];
  __shared__ float wshs[9][128];
  __shared__ float aas[128];
  __shared__ float als[128][4];
  __shared__ int   srcs[128];
  __shared__ int   dsts[128];
  int tid = threadIdx.x;
  int ty = tid >> 4, tx = tid & 15;
  int e0 = blockIdx.x * 128;
  int col0 = blockIdx.y * 128;
  for (int idx = tid; idx < 128*9; idx += 256) {
    int r = idx / 9, q = idx - r*9;
    shs[r][q] = shp[(size_t)(e0+r)*NSH + q];
  }
  for (int idx = tid; idx < 9*32; idx += 256) {
    int q = idx >> 5, cq = idx & 31;
    int col = col0 + cq*4;
    float4 v = make_float4(0.f,0.f,0.f,0.f);
    if (col < DIM) v = *(const float4*)(wsh + (size_t)q*DIM + col);
    *(float4*)&wshs[q][cq*4] = v;
  }
  if (tid < 128) {
    srcs[tid] = esrcp[e0 + tid];
    if (MODE == 0) {
      int col = col0 + tid;
      aas[tid] = (col < DIM) ? aa[col] : 0.f;
    }
    if (MODE == 1)
      *(float4*)&als[tid][0] = *(const float4*)(alpha + (size_t)(e0+tid)*NHEAD);
    if (MODE >= 1) dsts[tid] = edstp[e0 + tid];
  }
  float acc[8][8] = {};
  for (int k0 = 0; k0 < FCH; k0 += 32) {
    __syncthreads();
    for (int idx = tid; idx < 512; idx += 256) {       // h2 tile: 128 rows x 32 k (bf16)
      int el = idx >> 2, kq = idx & 3;
      uint4 raw = *(const uint4*)((const ushort*)h2 + (size_t)(e0+el)*FCH + k0 + kq*8);
      unsigned w[4] = {raw.x, raw.y, raw.z, raw.w};
#pragma unroll
      for (int m2 = 0; m2 < 4; m2++) {
        h2s[kq*8 + m2*2 + 0][el] = __uint_as_float((w[m2] & 0xffffu) << 16);
        h2s[kq*8 + m2*2 + 1][el] = __uint_as_float(w[m2] & 0xffff0000u);
      }
    }
    for (int idx = tid; idx < 1024; idx += 256) {      // w3 slice: 32 k x 128 cols (f32)
      int kk = idx >> 5, cq = idx & 31;
      int col = col0 + cq*4;
      float4 v = make_float4(0.f,0.f,0.f,0.f);
      if (col < DIM) v = *(const float4*)(w3 + (size_t)(k0+kk)*DIM + col);
      *(float4*)&w3s[kk][cq*4] = v;
    }
    __syncthreads();
#pragma unroll
    for (int kk = 0; kk < 32; kk++) {
      float4 a0 = *(const float4*)&h2s[kk][ty*8];
      float4 a1 = *(const float4*)&h2s[kk][ty*8+4];
      float4 b0 = *(const float4*)&w3s[kk][tx*4];
      float4 b1 = *(const float4*)&w3s[kk][64 + tx*4];
      float a[8] = {a0.x,a0.y,a0.z,a0.w,a1.x,a1.y,a1.z,a1.w};
      float b[8] = {b0.x,b0.y,b0.z,b0.w,b1.x,b1.y,b1.z,b1.w};
#pragma unroll
      for (int i = 0; i < 8; i++)
#pragma unroll
        for (int j = 0; j < 8; j++) acc[i][j] = fmaf(a[i], b[j], acc[i][j]);
    }
  }
  // epilogue
  int headA = col0 / HDIM;
  bool validB = (col0 + 64 + tx*4 + 3) < DIM;
  int headG0 = (col0 + tx*4) / HDIM;
  int headG1 = validB ? ((col0 + 64 + tx*4) / HDIM) : 0;
  float racc[8];
  int prev_dst = 0;
  if (MODE >= 1) {
#pragma unroll
    for (int j = 0; j < 8; j++) racc[j] = 0.f;
    prev_dst = dsts[ty*8];
  }
#pragma unroll
  for (int i = 0; i < 8; i++) {
    int el = ty*8 + i;
    int row = e0 + el;
    float sw[8];
#pragma unroll
    for (int j = 0; j < 8; j++) sw[j] = 0.f;
#pragma unroll
    for (int q = 0; q < 9; q++) {
      float shq = shs[el][q];
#pragma unroll
      for (int j = 0; j < 4; j++) {
        sw[j]   = fmaf(shq, wshs[q][tx*4 + j], sw[j]);
        sw[4+j] = fmaf(shq, wshs[q][64 + tx*4 + j], sw[4+j]);
      }
    }
    float vj[8];
    if (MODE == 2) {
#pragma unroll
      for (int j = 0; j < 8; j++) vj[j] = 1.f;
    } else {
      const ushort* yr = (const ushort*)y + (size_t)srcs[el]*DIM;
      uint2 y0 = *(const uint2*)(yr + col0 + tx*4);
      vj[0] = bf2f((ushort)(y0.x & 0xffffu)); vj[1] = bf2f((ushort)(y0.x >> 16));
      vj[2] = bf2f((ushort)(y0.y & 0xffffu)); vj[3] = bf2f((ushort)(y0.y >> 16));
      if (validB) {
        uint2 y1 = *(const uint2*)(yr + col0 + 64 + tx*4);
        vj[4] = bf2f((ushort)(y1.x & 0xffffu)); vj[5] = bf2f((ushort)(y1.x >> 16));
        vj[6] = bf2f((ushort)(y1.y & 0xffffu)); vj[7] = bf2f((ushort)(y1.y >> 16));
      } else { vj[4]=vj[5]=vj[6]=vj[7]=0.f; }
    }
    float m[8];
#pragma unroll
    for (int j = 0; j < 8; j++) m[j] = vj[j] * sw[j] * acc[i][j];

    if (MODE == 0) {
      float p0 = 0.f, p1 = 0.f;
#pragma unroll
      for (int j = 0; j < 4; j++) {
        float l0 = (m[j]   > 0.f) ? m[j]   : 0.2f*m[j];
        float l1 = (m[4+j] > 0.f) ? m[4+j] : 0.2f*m[4+j];
        p0 = fmaf(l0, aas[tx*4 + j], p0);
        p1 = fmaf(l1, aas[64 + tx*4 + j], p1);
      }
      float pA = (headG0 == headA) ? p0 : 0.f;
      float pB = (headG0 == headA) ? 0.f : p0;
      pA += (headG1 == headA) ? p1 : 0.f;
      pB += (headG1 == headA) ? 0.f : p1;
#pragma unroll
      for (int off = 8; off > 0; off >>= 1) {
        pA += __shfl_down(pA, off, 16);
        pB += __shfl_down(pB, off, 16);
      }
      if (tx == 0) {
        atomicAdd(&outbuf[(size_t)row*NHEAD + headA], pA);
        if (headA < 3 && (headA+1)*HDIM < col0 + 128)
          atomicAdd(&outbuf[(size_t)row*NHEAD + headA + 1], pB);
      }
    } else {
      float s0, s1;
      if (MODE == 1) { s0 = als[el][headG0]; s1 = als[el][headG1]; }
      else           { s0 = s1 = 1.0f/16.0f; }
      int dd = dsts[el];
      if (dd != prev_dst) {
        float* ar = outbuf + (size_t)prev_dst * DIM;
#pragma unroll
        for (int j = 0; j < 4; j++) atomicAdd(&ar[col0 + tx*4 + j], racc[j]);
        if (validB)
#pragma unroll
          for (int j = 0; j < 4; j++) atomicAdd(&ar[col0 + 64 + tx*4 + j], racc[4+j]);
#pragma unroll
        for (int j = 0; j < 8; j++) racc[j] = 0.f;
        prev_dst = dd;
      }
#pragma unroll
      for (int j = 0; j < 4; j++) { racc[j] = fmaf(m[j], s0, racc[j]); racc[4+j] = fmaf(m[4+j], s1, racc[4+j]); }
    }
  }
  if (MODE >= 1) {
    float* ar = outbuf + (size_t)prev_dst * DIM;
#pragma unroll
    for (int j = 0; j < 4; j++) atomicAdd(&ar[col0 + tx*4 + j], racc[j]);
    if (validB)
#pragma unroll
      for (int j = 0; j < 4; j++) atomicAdd(&ar[col0 + 64 + tx*4 + j], racc[4+j]);
  }
}

// ---------------- segment softmax ----------------
__global__ void k_alpha(const int* __restrict__ row_ptr, const float* __restrict__ logits,
                        float* __restrict__ alpha)
{
  int i = blockIdx.x * 256 + threadIdx.x;
  if (i >= NN * NHEAD) return;
  int d = i >> 2, h = i & 3;
  int beg = row_ptr[d], end = row_ptr[d+1];
  if (beg == end) return;
  float m = -1e30f;
  for (int j = beg; j < end; j++) m = fmaxf(m, logits[(size_t)j*NHEAD + h]);
  float s = 0.f;
  for (int j = beg; j < end; j++) {
    float ex = __expf(logits[(size_t)j*NHEAD + h] - m);
    alpha[(size_t)j*NHEAD + h] = ex;
    s += ex;
  }
  float inv = 1.f / (s + 1e-9f);
  for (int j = beg; j < end; j++) alpha[(size_t)j*NHEAD + h] *= inv;
}

// ---------------- x init: atom embedding gather ----------------
__global__ void k_init_x(const int* __restrict__ z, const float* __restrict__ emb,
                         float* __restrict__ x)
{
  int i = blockIdx.x * 256 + threadIdx.x;
  if (i >= NN * DIM) return;
  int n = i / DIM, c = i - n * DIM;
  x[i] = emb[(size_t)z[n]*DIM + c];
}

// ---------------- final scatter over molecules ----------------
__global__ void k_scatter(const float* __restrict__ h, const int* __restrict__ batch,
                          float* __restrict__ out)
{
  int i = blockIdx.x * 256 + threadIdx.x;
  if (i >= NN * NS) return;
  int n = i >> 7;
  atomicAdd(&out[(size_t)batch[n]*NS + (i & 127)], h[i] * 0.23570226039551584f);
}

extern "C" void kernel_launch(void* const* d_in, const int* in_sizes, int n_in,
                              void* d_out, int out_size, void* d_ws, size_t ws_size,
                              hipStream_t stream)
{
  const int*   z        = (const int*)  d_in[0];
  const float* pos      = (const float*)d_in[1];
  const int*   batch    = (const int*)  d_in[2];
  const int*   esrc     = (const int*)  d_in[3];
  const int*   edst     = (const int*)  d_in[4];
  const float* atom_emb = (const float*)d_in[5];
  const float* W_deg_sh = (const float*)d_in[6];
  const float* deg_w1   = (const float*)d_in[7];
  const float* deg_w2   = (const float*)d_in[8];
  const float* deg_w3   = (const float*)d_in[9];
  const float* Wv       = (const float*)d_in[10];
  const float* Wsh      = (const float*)d_in[11];
  const float* rad_w1   = (const float*)d_in[12];
  const float* rad_w2   = (const float*)d_in[13];
  const float* rad_w3   = (const float*)d_in[14];
  const float* attn_a   = (const float*)d_in[15];
  const float* Wo       = (const float*)d_in[16];
  const float* ffn_w1   = (const float*)d_in[17];
  const float* ffn_w2   = (const float*)d_in[18];
  const float* head_w1  = (const float*)d_in[19];
  const float* head_w2  = (const float*)d_in[20];
  float* out = (float*)d_out;

  // workspace (~87 MB)
  float* x      = (float*)d_ws;                       // [NN][480]
  float* statsb = x      + (size_t)NN * DIM;          // [NN][2]
  float* agg    = statsb + (size_t)NN * 2;            // [NN][480] (also ffn mid / head h1)
  float* tmp    = agg    + (size_t)NN * DIM;          // [NN][128]
  float* shp    = tmp    + (size_t)NN * NS;           // [NE][9]
  float* distp  = shp    + (size_t)NE * NSH;          // [NE]
  float* logitsb= distp  + (size_t)NE;                // [NE][4]
  float* alphab = logitsb+ (size_t)NE * NHEAD;        // [NE][4]
  __hip_bfloat16* yb  = (__hip_bfloat16*)(alphab + (size_t)NE * NHEAD);  // [NN][480]
  __hip_bfloat16* h2b = yb + (size_t)NN * DIM;        // [NE][64]
  int* cnt      = (int*)(h2b + (size_t)NE * FCH);
  int* row_ptr  = cnt + NN;
  int* csr      = row_ptr + NN + 1;
  int* cursor   = csr + NE;
  int* esrcp    = cursor + NN;
  int* edstp    = esrcp + NE;

  dim3 b256(256);
  // CSR build (dst-sorted edge permutation)
  k_zero_int<<<(NN+255)/256, b256, 0, stream>>>(cnt, NN);
  k_count<<<(NE+255)/256, b256, 0, stream>>>(edst, cnt);
  k_scan<<<1, 1024, 0, stream>>>(cnt, row_ptr);
  k_zero_int<<<(NN+255)/256, b256, 0, stream>>>(cursor, NN);
  k_fill<<<(NE+255)/256, b256, 0, stream>>>(edst, row_ptr, cursor, csr);
  k_geom_p<<<(NE+255)/256, b256, 0, stream>>>(pos, esrc, edst, csr, shp, distp, esrcp, edstp);

  dim3 msg_grid(NE/128, 4);
  // degree embedding: x = emb[z] + (1/16) * segsum(sw * gate)
  k_radial<<<NE/64, b256, 0, stream>>>(distp, deg_w1, deg_w2, h2b);
  k_init_x<<<(NN*DIM+255)/256, b256, 0, stream>>>(z, atom_emb, x);
  k_msg<2><<<msg_grid, b256, 0, stream>>>(h2b, shp, esrcp, edstp, deg_w3, W_deg_sh,
      nullptr, nullptr, nullptr, x);

  dim3 gemm_grid(79, 4);
  for (int l = 0; l < NL; l++) {
    const float* Wv_l  = Wv  + (size_t)l*DIM*DIM;
    const float* Wsh_l = Wsh + (size_t)l*NSH*DIM;
    const float* w1_l  = rad_w1 + (size_t)l*NBASIS*FCH;
    const float* w2_l  = rad_w2 + (size_t)l*FCH*FCH;
    const float* w3_l  = rad_w3 + (size_t)l*FCH*DIM;
    const float* aa_l  = attn_a + (size_t)l*NHEAD*HDIM;
    const float* Wo_l  = Wo  + (size_t)l*DIM*DIM;
    const float* f1_l  = ffn_w1 + (size_t)l*DIM*DIM;
    const float* f2_l  = ffn_w2 + (size_t)l*DIM*DIM;

    k_stats<<<(NN+3)/4, b256, 0, stream>>>(x, statsb, NN, DIM, DIM);
    k_gemm<0,0,1,1><<<gemm_grid, b256, 0, stream>>>(x, Wv_l, nullptr, yb, statsb,
        NN, DIM, DIM, DIM);                             // yb = LN(x) @ Wv (bf16)
    k_radial<<<NE/64, b256, 0, stream>>>(distp, w1_l, w2_l, h2b);
    hipMemsetAsync(logitsb, 0, (size_t)NE * NHEAD * sizeof(float), stream);
    k_msg<0><<<msg_grid, b256, 0, stream>>>(h2b, shp, esrcp, edstp, w3_l, Wsh_l,
        aa_l, yb, nullptr, logitsb);
    k_alpha<<<(NN*NHEAD+255)/256, b256, 0, stream>>>(row_ptr, logitsb, alphab);
    hipMemsetAsync(agg, 0, (size_t)NN * DIM * sizeof(float), stream);
    k_msg<1><<<msg_grid, b256, 0, stream>>>(h2b, shp, esrcp, edstp, w3_l, Wsh_l,
        nullptr, yb, alphab, agg);
    k_gemm<1,0,0,0><<<gemm_grid, b256, 0, stream>>>(agg, Wo_l, x, nullptr, nullptr,
        NN, DIM, DIM, DIM);                             // x += agg @ Wo
    k_stats<<<(NN+3)/4, b256, 0, stream>>>(x, statsb, NN, DIM, DIM);
    k_gemm<0,1,1,0><<<gemm_grid, b256, 0, stream>>>(x, f1_l, agg, nullptr, statsb,
        NN, DIM, DIM, DIM);                             // agg = silu(LN(x) @ W1)
    k_gemm<1,0,0,0><<<gemm_grid, b256, 0, stream>>>(agg, f2_l, x, nullptr, nullptr,
        NN, DIM, DIM, DIM);                             // x += agg @ W2
  }

  // output head: LN over first 128 cols, two 128x128 GEMMs, scatter
  k_stats<<<(NN+3)/4, b256, 0, stream>>>(x, statsb, NN, NS, DIM);
  dim3 head_grid(79, 1);
  k_gemm<0,1,1,0><<<head_grid, b256, 0, stream>>>(x, head_w1, agg, nullptr, statsb,
      NN, NS, NS, DIM);                                 // agg[:, :128] = silu(LN(s) @ w1)
  k_gemm<0,0,0,0><<<head_grid, b256, 0, stream>>>(agg, head_w2, tmp, nullptr, nullptr,
      NN, NS, NS, NS);
  hipMemsetAsync(d_out, 0, (size_t)NG * NS * sizeof(float), stream);
  k_scatter<<<(NN*NS+255)/256, b256, 0, stream>>>(tmp, batch, out);
}